// Round 6
// baseline (119.396 us; speedup 1.0000x reference)
//
#include <hip/hip_runtime.h>
#include <math.h>

#define NFFT 4096
#define HALF 2048
#define LSEG 2048   // L
#define SSZ 4096    // STATE_SIZE

typedef float v2f __attribute__((ext_vector_type(2)));
typedef float v4f __attribute__((ext_vector_type(4)));

// ---------------- verified packed-f32 complex primitives (R1/R3-passing set) ----------------
// cmul: r = {a.x*b.x - a.y*b.y, a.x*b.y + a.y*b.x}
static __device__ __forceinline__ v2f cmul(v2f a, v2f b) {
    v2f r;
    asm("v_pk_mul_f32 %0, %1, %2 op_sel:[0,0] op_sel_hi:[0,1]\n\t"
        "v_pk_fma_f32 %0, %1, %2, %0 op_sel:[1,1,0] op_sel_hi:[1,0,1] neg_lo:[1,0,0]"
        : "=&v"(r) : "v"(a), "v"(b));
    return r;
}
// c + {d.y, -d.x}   (forward -i rotation)
static __device__ __forceinline__ v2f cadd_mi(v2f c, v2f d) {
    v2f r;
    asm("v_pk_add_f32 %0, %1, %2 op_sel:[0,1] op_sel_hi:[1,0] neg_hi:[0,1]"
        : "=v"(r) : "v"(c), "v"(d));
    return r;
}
// c + {-d.y, d.x}   (inverse +i rotation)
static __device__ __forceinline__ v2f cadd_pi(v2f c, v2f d) {
    v2f r;
    asm("v_pk_add_f32 %0, %1, %2 op_sel:[0,1] op_sel_hi:[1,0] neg_lo:[0,1]"
        : "=v"(r) : "v"(c), "v"(d));
    return r;
}

// Bijective XOR swizzle (involution): keeps LDS at exactly 32 KiB (5 blocks/CU)
// while matching the old +pad layout's bank distribution for every access
// pattern in this kernel (verified per-pattern: 16 bank-pairs x 4 lanes = the
// 512B/4-cycle floor for 8B x 64-lane accesses).
static __device__ __forceinline__ int SWZ(int i) { return i ^ ((i >> 4) & 15); }

template <int SGN>
static __device__ __forceinline__ void dft16(v2f r[16]) {
    v2f t[16];
#pragma unroll
    for (int n1 = 0; n1 < 4; ++n1) {
        v2f a = r[n1], b = r[n1 + 4], c = r[n1 + 8], d = r[n1 + 12];
        v2f A = a + c, B = b + d, C = a - c, D = b - d;
        t[n1 * 4 + 0] = A + B;
        t[n1 * 4 + 2] = A - B;
        if (SGN < 0) {
            t[n1 * 4 + 1] = cadd_mi(C, D);
            t[n1 * 4 + 3] = cadd_pi(C, D);
        } else {
            t[n1 * 4 + 1] = cadd_pi(C, D);
            t[n1 * 4 + 3] = cadd_mi(C, D);
        }
    }
    const float CC[10] = {1.f, 0.92387953251f, 0.70710678119f, 0.38268343236f, 0.f,
                          -0.38268343236f, -0.70710678119f, -0.92387953251f, -1.f, -0.92387953251f};
    const float SS[10] = {0.f, 0.38268343236f, 0.70710678119f, 0.92387953251f, 1.f,
                          0.92387953251f, 0.70710678119f, 0.38268343236f, 0.f, -0.38268343236f};
    const float S = (float)SGN;
#pragma unroll
    for (int n1 = 1; n1 < 4; ++n1) {
#pragma unroll
        for (int m2 = 1; m2 < 4; ++m2) {
            const int k = n1 * m2;
            t[n1 * 4 + m2] = cmul(t[n1 * 4 + m2], (v2f){CC[k], S * SS[k]});
        }
    }
#pragma unroll
    for (int m2 = 0; m2 < 4; ++m2) {
        v2f a = t[m2], b = t[4 + m2], c = t[8 + m2], d = t[12 + m2];
        v2f A = a + c, B = b + d, C = a - c, D = b - d;
        r[m2]     = A + B;
        r[m2 + 8] = A - B;
        if (SGN < 0) {
            r[m2 + 4]  = cadd_mi(C, D);
            r[m2 + 12] = cadd_pi(C, D);
        } else {
            r[m2 + 4]  = cadd_pi(C, D);
            r[m2 + 12] = cadd_mi(C, D);
        }
    }
}

// apply r[m] *= w1^m via squaring tree (depth 4)
static __device__ __forceinline__ void twiddle_chain(v2f r[16], v2f w1) {
    v2f w2 = cmul(w1, w1);
    v2f w3 = cmul(w2, w1);
    v2f w4 = cmul(w2, w2);
    v2f w5 = cmul(w4, w1);
    v2f w6 = cmul(w4, w2);
    v2f w7 = cmul(w4, w3);
    v2f w8 = cmul(w4, w4);
    r[1] = cmul(r[1], w1);   r[2] = cmul(r[2], w2);
    r[3] = cmul(r[3], w3);   r[4] = cmul(r[4], w4);
    r[5] = cmul(r[5], w5);   r[6] = cmul(r[6], w6);
    r[7] = cmul(r[7], w7);   r[8] = cmul(r[8], w8);
    r[9]  = cmul(r[9],  cmul(w8, w1));
    r[10] = cmul(r[10], cmul(w8, w2));
    r[11] = cmul(r[11], cmul(w8, w3));
    r[12] = cmul(r[12], cmul(w8, w4));
    r[13] = cmul(r[13], cmul(w8, w5));
    r[14] = cmul(r[14], cmul(w8, w6));
    r[15] = cmul(r[15], cmul(w8, w7));
}

// One block per PAIR of batches, 256 threads, radix-16 FFT (R3 structure).
// LDS = exactly 32 KiB (XOR-swizzled layout, no pad) -> 5 blocks/CU.
// Coefs computed in-kernel by threads 0/128 (fp64), broadcast via workspace
// (block-level global visibility is fenced by __syncthreads).
__global__ __launch_bounds__(256, 5)
void preamp_fft_kernel(const float* __restrict__ x,
                       const float* __restrict__ state,
                       const float* __restrict__ cond,
                       const float* __restrict__ a_rg,
                       const float* __restrict__ a_r1,
                       const float* __restrict__ a_c1,
                       const float* __restrict__ a_c2,
                       const float* __restrict__ cond_w,
                       const float* __restrict__ cond_b,
                       float* __restrict__ cf_ws,
                       float* __restrict__ out, int B) {
    __shared__ v2f a_s[NFFT];               // exactly 32 KiB

    const int t = threadIdx.x;
    const int b0 = 2 * blockIdx.x;
    const int b1 = (b0 + 1 < B) ? b0 + 1 : b0;
    float* gcf = cf_ws + (size_t)blockIdx.x * 10;   // per-block coef slot

    const float* st0 = state + (size_t)b0 * SSZ + (SSZ - LSEG);
    const float* xb0 = x + (size_t)b0 * LSEG;
    const float* st1 = state + (size_t)b1 * SSZ + (SSZ - LSEG);
    const float* xb1 = x + (size_t)b1 * LSEG;

    // staging: vectorized float4 loads; the state/x split is uniform in q
#pragma unroll
    for (int q = 0; q < 4; ++q) {
        const int i0 = (t + 256 * q) << 2;   // multiple of 4, [0,4096)
        v4f fa, fb;
        if (q < 2) {
            fa = *(const v4f*)(st0 + i0);
            fb = *(const v4f*)(st1 + i0);
        } else {
            fa = *(const v4f*)(xb0 + (i0 - LSEG));
            fb = *(const v4f*)(xb1 + (i0 - LSEG));
        }
        a_s[SWZ(i0 + 0)] = (v2f){fa.x, fb.x};
        a_s[SWZ(i0 + 1)] = (v2f){fa.y, fb.y};
        a_s[SWZ(i0 + 2)] = (v2f){fa.z, fb.z};
        a_s[SWZ(i0 + 3)] = (v2f){fa.w, fb.w};
    }

    // ---- in-kernel coefficient computation (threads 0 and 128) ----
    if ((t & 127) == 0) {
        const int who = t >> 7;
        const int bb = who ? b1 : b0;

        const double RG = (0.9 + (double)(1.0f / (1.0f + expf(-a_rg[0]))) * 0.2) * 1.0e6;
        const double R1 = (0.99 + (double)(1.0f / (1.0f + expf(-a_r1[0]))) * 0.02) * 4.7e5;
        const double C1 = (0.9 + (double)(1.0f / (1.0f + expf(-a_c1[0]))) * 0.2) * 3.3e-9;
        const double C2 = (0.9 + (double)(1.0f / (1.0f + expf(-a_c2[0]))) * 0.2) * 1.0e-9;
        const double g1 = 1.0 / R1;
        const double gc1 = 2.0 * C1 * 44100.0;
        const double gc2 = 2.0 * C2 * 44100.0;

        float zf = cond[bb] * cond_w[0] + cond_b[0];
        float pot = 1.0f / (1.0f + expf(-zf));
        float prf = (powf(10.0f, pot) - 1.0f) / 9.0f;
        prf = fminf(fmaxf(prf, 1e-4f), 1.0f - 1e-4f);
        const double p = (double)prf;

        // Analytic So^{-1}
        const double ds = gc1 + g1;
        double S[4][4] = {
            {0.0, 0.0,        0.0,       1.0},
            {0.0, 1.0 / ds,   0.0,       gc1 / ds},
            {0.0, 0.0,        1.0 / gc2, 0.0},
            {1.0, gc1 / ds,   0.0,       -gc1 * g1 / ds}};

        double Q00 = S[1][1] - S[1][2] - S[2][1] + S[2][2];
        double Q01 = S[1][2] - S[2][2];
        double Q10 = S[2][1] - S[2][2];
        double Q11 = S[2][2];

        double Ux00 = S[0][1] - S[0][2] - S[1][1] + S[1][2];
        double Ux01 = S[0][2] - S[1][2];
        double Ux10 = S[2][1] - S[2][2];
        double Ux11 = S[2][2];

        double Uo0 = S[2][1] - S[2][2], Uo1 = S[2][2];
        double Uu0 = S[3][1] - S[3][2], Uu1 = S[3][2];

        double P00 = S[0][0] - S[0][1] - S[1][0] + S[1][1];
        double P01 = S[0][2] - S[1][2];
        double P10 = S[2][0] - S[2][1];
        double P11 = S[2][2];

        double Ao00 = 2.0 * gc1 * P00 - 1.0, Ao01 = 2.0 * gc1 * P01;
        double Ao10 = 2.0 * gc2 * P10,       Ao11 = 2.0 * gc2 * P11 - 1.0;

        double Bo0 = 2.0 * gc1 * (S[0][3] - S[1][3]);
        double Bo1 = 2.0 * gc2 * S[2][3];

        double Do0 = S[2][0] - S[2][1], Do1 = S[2][2];
        double Eo  = S[2][3];

        double T00 = 2.0 * gc1 * Ux00, T01 = 2.0 * gc1 * Ux01;
        double T10 = 2.0 * gc2 * Ux10, T11 = 2.0 * gc2 * Ux11;

        double d0 = (1.0 - p) * RG, d1v = p * RG;
        double M00 = d0 + Q00, M01 = Q01, M10 = Q10, M11 = d1v + Q11;
        double idet = 1.0 / (M00 * M11 - M01 * M10);
        double G00 =  M11 * idet, G01 = -M01 * idet;
        double G10 = -M10 * idet, G11 =  M00 * idet;

        double TG00 = T00 * G00 + T01 * G10, TG01 = T00 * G01 + T01 * G11;
        double TG10 = T10 * G00 + T11 * G10, TG11 = T10 * G01 + T11 * G11;

        double A00 = Ao00 - (TG00 * Ux00 + TG01 * Ux01);
        double A01 = Ao01 - (TG00 * Ux10 + TG01 * Ux11);
        double A10 = Ao10 - (TG10 * Ux00 + TG11 * Ux01);
        double A11 = Ao11 - (TG10 * Ux10 + TG11 * Ux11);

        double Bm0 = Bo0 - (TG00 * Uu0 + TG01 * Uu1);
        double Bm1 = Bo1 - (TG10 * Uu0 + TG11 * Uu1);

        double w0v = Uo0 * G00 + Uo1 * G10, w1v = Uo0 * G01 + Uo1 * G11;
        double Dm0 = Do0 - (w0v * Ux00 + w1v * Ux01);
        double Dm1 = Do1 - (w0v * Ux10 + w1v * Ux11);
        double Em  = Eo  - (w0v * Uu0 + w1v * Uu1);

        double den1 = -(A00 + A11);
        double den2 = A00 * A11 - A01 * A10;
        double Mm00 = A00 - Bm0 * Dm0, Mm01 = A01 - Bm0 * Dm1;
        double Mm10 = A10 - Bm1 * Dm0, Mm11 = A11 - Bm1 * Dm1;
        double num0 = Em;
        double num1 = -(Mm00 + Mm11) + (Em - 1.0) * den1;
        double num2 = (Mm00 * Mm11 - Mm01 * Mm10) + (Em - 1.0) * den2;

        // interleaved {a,b}; numerator pre-scaled by 0.5 (exact pow-2)
        gcf[0 + who] = (float)(0.5 * num0);
        gcf[2 + who] = (float)(0.5 * num1);
        gcf[4 + who] = (float)(0.5 * (num0 + num1 + num2));   // 0.5*num(1), fp64 sum
        gcf[6 + who] = (float)den1;
        gcf[8 + who] = (float)(1.0 + den1 + den2);            // den(1), fp64 sum
    }
    __syncthreads();   // fences LDS staging AND the gcf global writes (block scope)

    const float TW4096 = 0.00153398078788564f;   // 2*pi/4096
    const float TW256  = 0.02454369260617026f;   // 2*pi/256
    const float HW4096 = 0.00076699039394282f;   // pi/4096

    // cached twiddle angles, shared between forward and inverse passes
    float swA, cwA;
    __sincosf((float)t * TW4096, &swA, &cwA);
    const int subB = t >> 4, jB = t & 15;
    float swB, cwB;
    __sincosf((float)jB * TW256, &swB, &cwB);

    v2f r[16];

    // ---- forward pass A: span 256 ----
#pragma unroll
    for (int m = 0; m < 16; ++m) r[m] = a_s[SWZ(t + 256 * m)];
    dft16<-1>(r);
    twiddle_chain(r, (v2f){cwA, -swA});
#pragma unroll
    for (int m = 0; m < 16; ++m) a_s[SWZ(t + 256 * m)] = r[m];
    __syncthreads();

    // ---- forward pass B: span 16 within 256-blocks ----
    {
        const int base = subB * 256 + jB;
#pragma unroll
        for (int m = 0; m < 16; ++m) r[m] = a_s[SWZ(base + 16 * m)];
        dft16<-1>(r);
        twiddle_chain(r, (v2f){cwB, -swB});
#pragma unroll
        for (int m = 0; m < 16; ++m) a_s[SWZ(base + 16 * m)] = r[m];
    }
    __syncthreads();

    // ---- forward span-1 DFT, scatter to natural order ----
    {
        const int base = 16 * t;
#pragma unroll
        for (int m = 0; m < 16; ++m) r[m] = a_s[SWZ(base + m)];
        dft16<-1>(r);
        const int klo = ((t & 15) << 4) | (t >> 4);
        __syncthreads();
#pragma unroll
        for (int m = 0; m < 16; ++m) a_s[SWZ((m << 8) | klo)] = r[m];
    }
    __syncthreads();

    // ---- pointwise over Hermitian pairs (k, N-k), uniform 8 iters ----
    {
        const v2f n0p = *(const v2f*)(gcf + 0);
        const v2f n1p = *(const v2f*)(gcf + 2);
        const v2f snp = *(const v2f*)(gcf + 4);
        const v2f d1p = *(const v2f*)(gcf + 6);
        const v2f sdp = *(const v2f*)(gcf + 8);

        for (int j = 0; j < 8; ++j) {
            const int k  = t + 256 * j;                 // 0..2047
            const int kr = (NFFT - k) & (NFFT - 1);
            v2f Wk = a_s[SWZ(k)];
            v2f Wr = a_s[SWZ(kr)];
            // unscaled Hermitian split (0.5 folded into numerator coefs)
            float Xar = Wk.x + Wr.x, Xai = Wk.y - Wr.y;
            float Xbr = Wk.y + Wr.y, Xbi = Wr.x - Wk.x;
            // u = z-1 = -2*sin(th/2)*(sin(th/2), cos(th/2)), z = e^{-i th}
            float sh, ch;
            __sincosf((float)k * HW4096, &sh, &ch);
            float m2s = -2.0f * sh;
            float ur = m2s * sh, ui = m2s * ch, pr = ur + 2.0f;
            v2f urp = {ur, ur}, uip = {ui, ui}, prp = {pr, pr};

            v2f tr = n0p * prp + n1p;                   // n0*(z+1).re + n1
            v2f ti = n0p * uip;                         // n0*(z+1).im
            v2f nr = snp + urp * tr - uip * ti;
            v2f ni = urp * ti + uip * tr;
            v2f tb = prp + d1p;                         // (z+1).re + d1
            v2f dr = sdp + urp * tb - uip * uip;
            v2f di = urp * uip + uip * tb;
            v2f mg = dr * dr + di * di;
            v2f iv = { __builtin_amdgcn_rcpf(mg.x), __builtin_amdgcn_rcpf(mg.y) };
            v2f Hr = (nr * dr + ni * di) * iv;
            v2f Hi = (ni * dr - nr * di) * iv;

            float Yar = Hr.x * Xar - Hi.x * Xai, Yai = Hr.x * Xai + Hi.x * Xar;
            float Ybr = Hr.y * Xbr - Hi.y * Xbi, Ybi = Hr.y * Xbi + Hi.y * Xbr;
            // Y[k] = Ya + i*Yb ; Y[N-k] = conj(Ya) + i*conj(Yb)
            // (at k=0, kr==k and both expressions coincide since Yai=Ybi=0)
            a_s[SWZ(k)]  = (v2f){Yar - Ybi, Yai + Ybr};
            a_s[SWZ(kr)] = (v2f){Yar + Ybi, Ybr - Yai};
        }
        // Nyquist bin k = 2048: z = -1, u = -2, (z+1) = 0 -> H is real
        if (t == 0) {
            v2f Wn = a_s[SWZ(2048)];
            float Ha = (snp.x - 2.0f * n1p.x) / (sdp.x - 2.0f * d1p.x);
            float Hb = (snp.y - 2.0f * n1p.y) / (sdp.y - 2.0f * d1p.y);
            a_s[SWZ(2048)] = (v2f){Ha * (2.0f * Wn.x), Hb * (2.0f * Wn.y)};
        }
    }
    __syncthreads();

    // ---- inverse span-1: gather from natural order, DFT, store base layout ----
    {
        const int base = 16 * t;
        const int klo = ((t & 15) << 4) | (t >> 4);
#pragma unroll
        for (int m = 0; m < 16; ++m) r[m] = a_s[SWZ((m << 8) | klo)];
        dft16<1>(r);
        __syncthreads();
#pragma unroll
        for (int m = 0; m < 16; ++m) a_s[SWZ(base + m)] = r[m];
    }
    __syncthreads();

    // ---- inverse pass B ----
    {
        const int base = subB * 256 + jB;
#pragma unroll
        for (int m = 0; m < 16; ++m) r[m] = a_s[SWZ(base + 16 * m)];
        twiddle_chain(r, (v2f){cwB, swB});
        dft16<1>(r);
#pragma unroll
        for (int m = 0; m < 16; ++m) a_s[SWZ(base + 16 * m)] = r[m];
    }
    __syncthreads();

    // ---- inverse pass A + direct store of last 2048 samples of both batches ----
    {
#pragma unroll
        for (int m = 0; m < 16; ++m) r[m] = a_s[SWZ(t + 256 * m)];
        twiddle_chain(r, (v2f){cwA, swA});
        dft16<1>(r);
        const float scale = 1.0f / (float)NFFT;
        float* ob0 = out + (size_t)b0 * LSEG;
        float* ob1 = out + (size_t)b1 * LSEG;
#pragma unroll
        for (int m = 8; m < 16; ++m) {
            const int idx = t + 256 * (m - 8);
            float ya = r[m].x * scale;
            float yb = (b1 != b0) ? r[m].y * scale : ya;
            ob0[idx] = ya;
            ob1[idx] = yb;
        }
    }
}

extern "C" void kernel_launch(void* const* d_in, const int* in_sizes, int n_in,
                              void* d_out, int out_size, void* d_ws, size_t ws_size,
                              hipStream_t stream) {
    const float* x     = (const float*)d_in[0];
    const float* cond  = (const float*)d_in[1];
    const float* state = (const float*)d_in[2];
    const float* a_rg  = (const float*)d_in[3];
    const float* a_r1  = (const float*)d_in[4];
    const float* a_c1  = (const float*)d_in[5];
    const float* a_c2  = (const float*)d_in[6];
    const float* c_w   = (const float*)d_in[7];
    const float* c_b   = (const float*)d_in[8];
    float* out = (float*)d_out;

    const int B = in_sizes[1];          // cond is [B,1]
    float* cf_ws = (float*)d_ws;        // ((B+1)/2) * 10 floats

    preamp_fft_kernel<<<dim3((B + 1) / 2), dim3(256), 0, stream>>>(
        x, state, cond, a_rg, a_r1, a_c1, a_c2, c_w, c_b, cf_ws, out, B);
}

// Round 7
// 113.933 us; speedup vs baseline: 1.0479x; 1.0479x over previous
//
#include <hip/hip_runtime.h>
#include <math.h>

#define NFFT 4096
#define HALF 2048
#define LSEG 2048   // L
#define SSZ 4096    // STATE_SIZE

typedef float v2f __attribute__((ext_vector_type(2)));

// ---------------- verified packed-f32 complex primitives (R1/R3-passing set) ----------------
// cmul: r = {a.x*b.x - a.y*b.y, a.x*b.y + a.y*b.x}
static __device__ __forceinline__ v2f cmul(v2f a, v2f b) {
    v2f r;
    asm("v_pk_mul_f32 %0, %1, %2 op_sel:[0,0] op_sel_hi:[0,1]\n\t"
        "v_pk_fma_f32 %0, %1, %2, %0 op_sel:[1,1,0] op_sel_hi:[1,0,1] neg_lo:[1,0,0]"
        : "=&v"(r) : "v"(a), "v"(b));
    return r;
}
// c + {d.y, -d.x}   (forward -i rotation)
static __device__ __forceinline__ v2f cadd_mi(v2f c, v2f d) {
    v2f r;
    asm("v_pk_add_f32 %0, %1, %2 op_sel:[0,1] op_sel_hi:[1,0] neg_hi:[0,1]"
        : "=v"(r) : "v"(c), "v"(d));
    return r;
}
// c + {-d.y, d.x}   (inverse +i rotation)
static __device__ __forceinline__ v2f cadd_pi(v2f c, v2f d) {
    v2f r;
    asm("v_pk_add_f32 %0, %1, %2 op_sel:[0,1] op_sel_hi:[1,0] neg_lo:[0,1]"
        : "=v"(r) : "v"(c), "v"(d));
    return r;
}

static __device__ __forceinline__ int PAD(int i) { return i + (i >> 4); }

template <int SGN>
static __device__ __forceinline__ void dft16(v2f r[16]) {
    v2f t[16];
#pragma unroll
    for (int n1 = 0; n1 < 4; ++n1) {
        v2f a = r[n1], b = r[n1 + 4], c = r[n1 + 8], d = r[n1 + 12];
        v2f A = a + c, B = b + d, C = a - c, D = b - d;
        t[n1 * 4 + 0] = A + B;
        t[n1 * 4 + 2] = A - B;
        if (SGN < 0) {
            t[n1 * 4 + 1] = cadd_mi(C, D);
            t[n1 * 4 + 3] = cadd_pi(C, D);
        } else {
            t[n1 * 4 + 1] = cadd_pi(C, D);
            t[n1 * 4 + 3] = cadd_mi(C, D);
        }
    }
    const float CC[10] = {1.f, 0.92387953251f, 0.70710678119f, 0.38268343236f, 0.f,
                          -0.38268343236f, -0.70710678119f, -0.92387953251f, -1.f, -0.92387953251f};
    const float SS[10] = {0.f, 0.38268343236f, 0.70710678119f, 0.92387953251f, 1.f,
                          0.92387953251f, 0.70710678119f, 0.38268343236f, 0.f, -0.38268343236f};
    const float S = (float)SGN;
#pragma unroll
    for (int n1 = 1; n1 < 4; ++n1) {
#pragma unroll
        for (int m2 = 1; m2 < 4; ++m2) {
            const int k = n1 * m2;
            t[n1 * 4 + m2] = cmul(t[n1 * 4 + m2], (v2f){CC[k], S * SS[k]});
        }
    }
#pragma unroll
    for (int m2 = 0; m2 < 4; ++m2) {
        v2f a = t[m2], b = t[4 + m2], c = t[8 + m2], d = t[12 + m2];
        v2f A = a + c, B = b + d, C = a - c, D = b - d;
        r[m2]     = A + B;
        r[m2 + 8] = A - B;
        if (SGN < 0) {
            r[m2 + 4]  = cadd_mi(C, D);
            r[m2 + 12] = cadd_pi(C, D);
        } else {
            r[m2 + 4]  = cadd_pi(C, D);
            r[m2 + 12] = cadd_mi(C, D);
        }
    }
}

// apply r[m] *= w1^m via squaring tree (depth 4)
static __device__ __forceinline__ void twiddle_chain(v2f r[16], v2f w1) {
    v2f w2 = cmul(w1, w1);
    v2f w3 = cmul(w2, w1);
    v2f w4 = cmul(w2, w2);
    v2f w5 = cmul(w4, w1);
    v2f w6 = cmul(w4, w2);
    v2f w7 = cmul(w4, w3);
    v2f w8 = cmul(w4, w4);
    r[1] = cmul(r[1], w1);   r[2] = cmul(r[2], w2);
    r[3] = cmul(r[3], w3);   r[4] = cmul(r[4], w4);
    r[5] = cmul(r[5], w5);   r[6] = cmul(r[6], w6);
    r[7] = cmul(r[7], w7);   r[8] = cmul(r[8], w8);
    r[9]  = cmul(r[9],  cmul(w8, w1));
    r[10] = cmul(r[10], cmul(w8, w2));
    r[11] = cmul(r[11], cmul(w8, w3));
    r[12] = cmul(r[12], cmul(w8, w4));
    r[13] = cmul(r[13], cmul(w8, w5));
    r[14] = cmul(r[14], cmul(w8, w6));
    r[15] = cmul(r[15], cmul(w8, w7));
}

// One block per PAIR of batches, 256 threads, radix-16 FFT (R3 structure).
// R7 deltas vs R3: (1) staging phase removed -- pass A loads its stride-256
// elements directly from global (coalesced across lanes), killing 1 barrier
// and 32 LDS ops; (2) pointwise uses a z-recursion (z *= e^{-i*2pi*256/4096})
// instead of 8 per-iteration __sincosf, reusing the pass-A twiddle angle as z0.
__global__ __launch_bounds__(256, 4)
void preamp_fft_kernel(const float* __restrict__ x,
                       const float* __restrict__ state,
                       const float* __restrict__ cond,
                       const float* __restrict__ a_rg,
                       const float* __restrict__ a_r1,
                       const float* __restrict__ a_c1,
                       const float* __restrict__ a_c2,
                       const float* __restrict__ cond_w,
                       const float* __restrict__ cond_b,
                       float* __restrict__ out, int B) {
    __shared__ v2f a_s[NFFT + NFFT / 16];   // padded: 34 KB
    __shared__ float cf[10];                // 2 batches x {n0,n1,sn,d1,sd}

    const int t = threadIdx.x;
    const int b0 = 2 * blockIdx.x;
    const int b1 = (b0 + 1 < B) ? b0 + 1 : b0;

    const float* st0 = state + (size_t)b0 * SSZ + (SSZ - LSEG);
    const float* xb0 = x + (size_t)b0 * LSEG;
    const float* st1 = state + (size_t)b1 * SSZ + (SSZ - LSEG);
    const float* xb1 = x + (size_t)b1 * LSEG;

    v2f r[16];

    // ---- direct global->register load of pass-A inputs (coalesced per m) ----
#pragma unroll
    for (int m = 0; m < 16; ++m) {
        const int i = t + 256 * m;
        float fa, fb;
        if (m < 8) { fa = st0[i]; fb = st1[i]; }
        else       { fa = xb0[i - LSEG]; fb = xb1[i - LSEG]; }
        r[m] = (v2f){fa, fb};
    }

    // ---- in-kernel coefficient computation (threads 0 and 128) ----
    // (runs while the global loads above are in flight)
    if ((t & 127) == 0) {
        const int who = t >> 7;
        const int bb = who ? b1 : b0;

        const double RG = (0.9 + (double)(1.0f / (1.0f + expf(-a_rg[0]))) * 0.2) * 1.0e6;
        const double R1 = (0.99 + (double)(1.0f / (1.0f + expf(-a_r1[0]))) * 0.02) * 4.7e5;
        const double C1 = (0.9 + (double)(1.0f / (1.0f + expf(-a_c1[0]))) * 0.2) * 3.3e-9;
        const double C2 = (0.9 + (double)(1.0f / (1.0f + expf(-a_c2[0]))) * 0.2) * 1.0e-9;
        const double g1 = 1.0 / R1;
        const double gc1 = 2.0 * C1 * 44100.0;
        const double gc2 = 2.0 * C2 * 44100.0;

        float zf = cond[bb] * cond_w[0] + cond_b[0];
        float pot = 1.0f / (1.0f + expf(-zf));
        float prf = (powf(10.0f, pot) - 1.0f) / 9.0f;
        prf = fminf(fmaxf(prf, 1e-4f), 1.0f - 1e-4f);
        const double p = (double)prf;

        // Analytic So^{-1}
        const double ds = gc1 + g1;
        double S[4][4] = {
            {0.0, 0.0,        0.0,       1.0},
            {0.0, 1.0 / ds,   0.0,       gc1 / ds},
            {0.0, 0.0,        1.0 / gc2, 0.0},
            {1.0, gc1 / ds,   0.0,       -gc1 * g1 / ds}};

        double Q00 = S[1][1] - S[1][2] - S[2][1] + S[2][2];
        double Q01 = S[1][2] - S[2][2];
        double Q10 = S[2][1] - S[2][2];
        double Q11 = S[2][2];

        double Ux00 = S[0][1] - S[0][2] - S[1][1] + S[1][2];
        double Ux01 = S[0][2] - S[1][2];
        double Ux10 = S[2][1] - S[2][2];
        double Ux11 = S[2][2];

        double Uo0 = S[2][1] - S[2][2], Uo1 = S[2][2];
        double Uu0 = S[3][1] - S[3][2], Uu1 = S[3][2];

        double P00 = S[0][0] - S[0][1] - S[1][0] + S[1][1];
        double P01 = S[0][2] - S[1][2];
        double P10 = S[2][0] - S[2][1];
        double P11 = S[2][2];

        double Ao00 = 2.0 * gc1 * P00 - 1.0, Ao01 = 2.0 * gc1 * P01;
        double Ao10 = 2.0 * gc2 * P10,       Ao11 = 2.0 * gc2 * P11 - 1.0;

        double Bo0 = 2.0 * gc1 * (S[0][3] - S[1][3]);
        double Bo1 = 2.0 * gc2 * S[2][3];

        double Do0 = S[2][0] - S[2][1], Do1 = S[2][2];
        double Eo  = S[2][3];

        double T00 = 2.0 * gc1 * Ux00, T01 = 2.0 * gc1 * Ux01;
        double T10 = 2.0 * gc2 * Ux10, T11 = 2.0 * gc2 * Ux11;

        double d0 = (1.0 - p) * RG, d1v = p * RG;
        double M00 = d0 + Q00, M01 = Q01, M10 = Q10, M11 = d1v + Q11;
        double idet = 1.0 / (M00 * M11 - M01 * M10);
        double G00 =  M11 * idet, G01 = -M01 * idet;
        double G10 = -M10 * idet, G11 =  M00 * idet;

        double TG00 = T00 * G00 + T01 * G10, TG01 = T00 * G01 + T01 * G11;
        double TG10 = T10 * G00 + T11 * G10, TG11 = T10 * G01 + T11 * G11;

        double A00 = Ao00 - (TG00 * Ux00 + TG01 * Ux01);
        double A01 = Ao01 - (TG00 * Ux10 + TG01 * Ux11);
        double A10 = Ao10 - (TG10 * Ux00 + TG11 * Ux01);
        double A11 = Ao11 - (TG10 * Ux10 + TG11 * Ux11);

        double Bm0 = Bo0 - (TG00 * Uu0 + TG01 * Uu1);
        double Bm1 = Bo1 - (TG10 * Uu0 + TG11 * Uu1);

        double w0v = Uo0 * G00 + Uo1 * G10, w1v = Uo0 * G01 + Uo1 * G11;
        double Dm0 = Do0 - (w0v * Ux00 + w1v * Ux01);
        double Dm1 = Do1 - (w0v * Ux10 + w1v * Ux11);
        double Em  = Eo  - (w0v * Uu0 + w1v * Uu1);

        double den1 = -(A00 + A11);
        double den2 = A00 * A11 - A01 * A10;
        double Mm00 = A00 - Bm0 * Dm0, Mm01 = A01 - Bm0 * Dm1;
        double Mm10 = A10 - Bm1 * Dm0, Mm11 = A11 - Bm1 * Dm1;
        double num0 = Em;
        double num1 = -(Mm00 + Mm11) + (Em - 1.0) * den1;
        double num2 = (Mm00 * Mm11 - Mm01 * Mm10) + (Em - 1.0) * den2;

        cf[who * 5 + 0] = (float)num0;
        cf[who * 5 + 1] = (float)num1;
        cf[who * 5 + 2] = (float)(num0 + num1 + num2);   // sn = num(1), fp64 sum
        cf[who * 5 + 3] = (float)den1;
        cf[who * 5 + 4] = (float)(1.0 + den1 + den2);    // sd = den(1), fp64 sum
    }

    const float TW4096 = 0.00153398078788564f;   // 2*pi/4096
    const float TW256  = 0.02454369260617026f;   // 2*pi/256

    // cached twiddle angles, shared between forward and inverse passes
    float swA, cwA;
    __sincosf((float)t * TW4096, &swA, &cwA);
    const int subB = t >> 4, jB = t & 15;
    float swB, cwB;
    __sincosf((float)jB * TW256, &swB, &cwB);

    // ---- forward pass A: span 256 (inputs already in registers) ----
    dft16<-1>(r);
    twiddle_chain(r, (v2f){cwA, -swA});
#pragma unroll
    for (int m = 0; m < 16; ++m) a_s[PAD(t + 256 * m)] = r[m];
    __syncthreads();   // fences pass-A LDS writes AND the cf writes

    // ---- forward pass B: span 16 within 256-blocks ----
    {
        const int base = subB * 256 + jB;
#pragma unroll
        for (int m = 0; m < 16; ++m) r[m] = a_s[PAD(base + 16 * m)];
        dft16<-1>(r);
        twiddle_chain(r, (v2f){cwB, -swB});
#pragma unroll
        for (int m = 0; m < 16; ++m) a_s[PAD(base + 16 * m)] = r[m];
    }
    __syncthreads();

    // ---- forward span-1 DFT, scatter to natural order ----
    {
        const int base = 16 * t;
#pragma unroll
        for (int m = 0; m < 16; ++m) r[m] = a_s[PAD(base + m)];
        dft16<-1>(r);
        const int klo = ((t & 15) << 4) | (t >> 4);
        __syncthreads();
#pragma unroll
        for (int m = 0; m < 16; ++m) a_s[PAD((m << 8) | klo)] = r[m];
    }
    __syncthreads();

    // ---- pointwise over Hermitian pairs (k, N-k), uniform 8 iters ----
    // z-recursion: z_j = e^{-i*2pi*(t+256j)/4096}; z_0 = {cwA, -swA};
    // z_{j+1} = z_j * W, W = e^{-i*2pi*256/4096} = {cos(pi/8), -sin(pi/8)}.
    {
        // 0.5 Hermitian factor folded into numerator coefs (exact pow-2 scale)
        const v2f n0p = {0.5f * cf[0], 0.5f * cf[5]};
        const v2f n1p = {0.5f * cf[1], 0.5f * cf[6]};
        const v2f snp = {0.5f * cf[2], 0.5f * cf[7]};
        const v2f d1p = {cf[3], cf[8]};
        const v2f sdp = {cf[4], cf[9]};
        const v2f Wstep = {0.92387953251f, -0.38268343236f};   // e^{-i pi/8}

        v2f z = {cwA, -swA};
        for (int j = 0; j < 8; ++j) {
            const int k  = t + 256 * j;                 // 0..2047
            const int kr = (NFFT - k) & (NFFT - 1);
            v2f Wk = a_s[PAD(k)];
            v2f Wr = a_s[PAD(kr)];
            // unscaled Hermitian split (0.5 folded into numerator coefs)
            float Xar = Wk.x + Wr.x, Xai = Wk.y - Wr.y;
            float Xbr = Wk.y + Wr.y, Xbi = Wr.x - Wk.x;
            // u = z - 1; z+1 = {pr, ui}
            float ur = z.x - 1.0f, ui = z.y, pr = z.x + 1.0f;
            v2f urp = {ur, ur}, uip = {ui, ui}, prp = {pr, pr};

            v2f tr = n0p * prp + n1p;                   // n0*(z+1).re + n1
            v2f ti = n0p * uip;                         // n0*(z+1).im
            v2f nr = snp + urp * tr - uip * ti;
            v2f ni = urp * ti + uip * tr;
            v2f tb = prp + d1p;                         // (z+1).re + d1
            v2f dr = sdp + urp * tb - uip * uip;
            v2f di = urp * uip + uip * tb;
            v2f mg = dr * dr + di * di;
            v2f iv = { __builtin_amdgcn_rcpf(mg.x), __builtin_amdgcn_rcpf(mg.y) };
            v2f Hr = (nr * dr + ni * di) * iv;
            v2f Hi = (ni * dr - nr * di) * iv;

            float Yar = Hr.x * Xar - Hi.x * Xai, Yai = Hr.x * Xai + Hi.x * Xar;
            float Ybr = Hr.y * Xbr - Hi.y * Xbi, Ybi = Hr.y * Xbi + Hi.y * Xbr;
            // Y[k] = Ya + i*Yb ; Y[N-k] = conj(Ya) + i*conj(Yb)
            // (at k=0, kr==k and both expressions coincide since Yai=Ybi=0)
            a_s[PAD(k)]  = (v2f){Yar - Ybi, Yai + Ybr};
            a_s[PAD(kr)] = (v2f){Yar + Ybi, Ybr - Yai};

            z = cmul(z, Wstep);
        }
        // Nyquist bin k = 2048: z = -1, u = -2, (z+1) = 0 -> H is real
        if (t == 0) {
            v2f Wn = a_s[PAD(2048)];
            float Ha = (snp.x - 2.0f * n1p.x) / (sdp.x - 2.0f * d1p.x);
            float Hb = (snp.y - 2.0f * n1p.y) / (sdp.y - 2.0f * d1p.y);
            a_s[PAD(2048)] = (v2f){Ha * (2.0f * Wn.x), Hb * (2.0f * Wn.y)};
        }
    }
    __syncthreads();

    // ---- inverse span-1: gather from natural order, DFT, store base layout ----
    {
        const int base = 16 * t;
        const int klo = ((t & 15) << 4) | (t >> 4);
#pragma unroll
        for (int m = 0; m < 16; ++m) r[m] = a_s[PAD((m << 8) | klo)];
        dft16<1>(r);
        __syncthreads();
#pragma unroll
        for (int m = 0; m < 16; ++m) a_s[PAD(base + m)] = r[m];
    }
    __syncthreads();

    // ---- inverse pass B ----
    {
        const int base = subB * 256 + jB;
#pragma unroll
        for (int m = 0; m < 16; ++m) r[m] = a_s[PAD(base + 16 * m)];
        twiddle_chain(r, (v2f){cwB, swB});
        dft16<1>(r);
#pragma unroll
        for (int m = 0; m < 16; ++m) a_s[PAD(base + 16 * m)] = r[m];
    }
    __syncthreads();

    // ---- inverse pass A + direct store of last 2048 samples of both batches ----
    {
#pragma unroll
        for (int m = 0; m < 16; ++m) r[m] = a_s[PAD(t + 256 * m)];
        twiddle_chain(r, (v2f){cwA, swA});
        dft16<1>(r);
        const float scale = 1.0f / (float)NFFT;
        float* ob0 = out + (size_t)b0 * LSEG;
        float* ob1 = out + (size_t)b1 * LSEG;
#pragma unroll
        for (int m = 8; m < 16; ++m) {
            const int idx = t + 256 * (m - 8);
            float ya = r[m].x * scale;
            float yb = (b1 != b0) ? r[m].y * scale : ya;
            ob0[idx] = ya;
            ob1[idx] = yb;
        }
    }
}

extern "C" void kernel_launch(void* const* d_in, const int* in_sizes, int n_in,
                              void* d_out, int out_size, void* d_ws, size_t ws_size,
                              hipStream_t stream) {
    const float* x     = (const float*)d_in[0];
    const float* cond  = (const float*)d_in[1];
    const float* state = (const float*)d_in[2];
    const float* a_rg  = (const float*)d_in[3];
    const float* a_r1  = (const float*)d_in[4];
    const float* a_c1  = (const float*)d_in[5];
    const float* a_c2  = (const float*)d_in[6];
    const float* c_w   = (const float*)d_in[7];
    const float* c_b   = (const float*)d_in[8];
    float* out = (float*)d_out;

    const int B = in_sizes[1];          // cond is [B,1]

    preamp_fft_kernel<<<dim3((B + 1) / 2), dim3(256), 0, stream>>>(
        x, state, cond, a_rg, a_r1, a_c1, a_c2, c_w, c_b, out, B);
}

// Round 8
// 106.149 us; speedup vs baseline: 1.1248x; 1.0733x over previous
//
#include <hip/hip_runtime.h>
#include <math.h>

#define NFFT 4096
#define LSEG 2048   // L
#define SSZ 4096    // STATE_SIZE

typedef float v4f __attribute__((ext_vector_type(4)));

// The reference op  out = irfft(rfft(s) * H)[ -L: ]  with H = num(z)/den(z)
// (2nd-order rational, z = e^{-i theta}) is a CIRCULAR biquad filter.
// With the reference's z = e^{-i theta} convention the stable recursion runs
// anti-causally in natural time == causal biquad on the REVERSED signal
//   s'[m] = s[4095-m],  y'[m] = y[4095-m]:
//   y'[m] = n0 s'[m] + n1 s'[m-1] + n2 s'[m-2] - d1 y'[m-1] - d2 y'[m-2]
// Partial fractions (poles l1,l2 = eigenvalues of the DK A-matrix, real,
// distinct, in (0,1)):  y' = c0 s' + c1 w1 + c2 w2,  wi = li*wi + s'.
// Each wi is a weighted prefix scan; circular wrap is applied EXACTLY via
//   wi_per[m] = wi[m] + li^{m+1} * wi[4095] / (1 - li^4096).
// Output needs only m in [0,2048) of the reversed stream (threads 0..127).
__global__ __launch_bounds__(256, 4)
void preamp_iir_kernel(const float* __restrict__ x,
                       const float* __restrict__ state,
                       const float* __restrict__ cond,
                       const float* __restrict__ a_rg,
                       const float* __restrict__ a_r1,
                       const float* __restrict__ a_c1,
                       const float* __restrict__ a_c2,
                       const float* __restrict__ cond_w,
                       const float* __restrict__ cond_b,
                       float* __restrict__ out, int B) {
    __shared__ float cf[13];     // lam1,lam2,c0,c1,c2,f16a,f16b,l2a,l2b,f1ka,f1kb,ioma,iomb
    __shared__ float Tw[2][4];   // per-wave scan totals, per pole
    __shared__ float Tot[2];     // block totals (= w~[4095])

    const int t = threadIdx.x;
    const int b = blockIdx.x;
    const int lane = t & 63;
    const int wv = t >> 6;

    const float* xb  = x + (size_t)b * LSEG;
    const float* stb = state + (size_t)b * SSZ + (SSZ - LSEG);

    // ---- reversed load: s[j] = buf[4095 - (16t + j)], buf = [state_tail, x] ----
    // t<128 -> reversed indices fall in the x half; t>=128 -> state tail half.
    float s[16];
    if (t < 128) {
#pragma unroll
        for (int u = 0; u < 4; ++u) {
            const int g0 = 4092 - 16 * t - 4 * u;      // >= 2048
            v4f v = *(const v4f*)(xb + (g0 - LSEG));
            s[4 * u + 0] = v.w; s[4 * u + 1] = v.z;
            s[4 * u + 2] = v.y; s[4 * u + 3] = v.x;
        }
    } else {
#pragma unroll
        for (int u = 0; u < 4; ++u) {
            const int g0 = 4092 - 16 * t - 4 * u;      // in [0, 2044]
            v4f v = *(const v4f*)(stb + g0);
            s[4 * u + 0] = v.w; s[4 * u + 1] = v.z;
            s[4 * u + 2] = v.y; s[4 * u + 3] = v.x;
        }
    }

    // ---- coefficient computation (thread 0, fp64 DK-method algebra) ----
    if (t == 0) {
        const double RG = (0.9 + (double)(1.0f / (1.0f + expf(-a_rg[0]))) * 0.2) * 1.0e6;
        const double R1 = (0.99 + (double)(1.0f / (1.0f + expf(-a_r1[0]))) * 0.02) * 4.7e5;
        const double C1 = (0.9 + (double)(1.0f / (1.0f + expf(-a_c1[0]))) * 0.2) * 3.3e-9;
        const double C2 = (0.9 + (double)(1.0f / (1.0f + expf(-a_c2[0]))) * 0.2) * 1.0e-9;
        const double g1 = 1.0 / R1;
        const double gc1 = 2.0 * C1 * 44100.0;
        const double gc2 = 2.0 * C2 * 44100.0;

        float zf = cond[b] * cond_w[0] + cond_b[0];
        float pot = 1.0f / (1.0f + expf(-zf));
        float prf = (powf(10.0f, pot) - 1.0f) / 9.0f;
        prf = fminf(fmaxf(prf, 1e-4f), 1.0f - 1e-4f);
        const double p = (double)prf;

        // Analytic So^{-1}
        const double ds = gc1 + g1;
        double S[4][4] = {
            {0.0, 0.0,        0.0,       1.0},
            {0.0, 1.0 / ds,   0.0,       gc1 / ds},
            {0.0, 0.0,        1.0 / gc2, 0.0},
            {1.0, gc1 / ds,   0.0,       -gc1 * g1 / ds}};

        double Q00 = S[1][1] - S[1][2] - S[2][1] + S[2][2];
        double Q01 = S[1][2] - S[2][2];
        double Q10 = S[2][1] - S[2][2];
        double Q11 = S[2][2];

        double Ux00 = S[0][1] - S[0][2] - S[1][1] + S[1][2];
        double Ux01 = S[0][2] - S[1][2];
        double Ux10 = S[2][1] - S[2][2];
        double Ux11 = S[2][2];

        double Uo0 = S[2][1] - S[2][2], Uo1 = S[2][2];
        double Uu0 = S[3][1] - S[3][2], Uu1 = S[3][2];

        double P00 = S[0][0] - S[0][1] - S[1][0] + S[1][1];
        double P01 = S[0][2] - S[1][2];
        double P10 = S[2][0] - S[2][1];
        double P11 = S[2][2];

        double Ao00 = 2.0 * gc1 * P00 - 1.0, Ao01 = 2.0 * gc1 * P01;
        double Ao10 = 2.0 * gc2 * P10,       Ao11 = 2.0 * gc2 * P11 - 1.0;

        double Bo0 = 2.0 * gc1 * (S[0][3] - S[1][3]);
        double Bo1 = 2.0 * gc2 * S[2][3];

        double Do0 = S[2][0] - S[2][1], Do1 = S[2][2];
        double Eo  = S[2][3];

        double T00 = 2.0 * gc1 * Ux00, T01 = 2.0 * gc1 * Ux01;
        double T10 = 2.0 * gc2 * Ux10, T11 = 2.0 * gc2 * Ux11;

        double d0 = (1.0 - p) * RG, d1v = p * RG;
        double M00 = d0 + Q00, M01 = Q01, M10 = Q10, M11 = d1v + Q11;
        double idet = 1.0 / (M00 * M11 - M01 * M10);
        double G00 =  M11 * idet, G01 = -M01 * idet;
        double G10 = -M10 * idet, G11 =  M00 * idet;

        double TG00 = T00 * G00 + T01 * G10, TG01 = T00 * G01 + T01 * G11;
        double TG10 = T10 * G00 + T11 * G10, TG11 = T10 * G01 + T11 * G11;

        double A00 = Ao00 - (TG00 * Ux00 + TG01 * Ux01);
        double A01 = Ao01 - (TG00 * Ux10 + TG01 * Ux11);
        double A10 = Ao10 - (TG10 * Ux00 + TG11 * Ux01);
        double A11 = Ao11 - (TG10 * Ux10 + TG11 * Ux11);

        double Bm0 = Bo0 - (TG00 * Uu0 + TG01 * Uu1);
        double Bm1 = Bo1 - (TG10 * Uu0 + TG11 * Uu1);

        double w0v = Uo0 * G00 + Uo1 * G10, w1v = Uo0 * G01 + Uo1 * G11;
        double Dm0 = Do0 - (w0v * Ux00 + w1v * Ux01);
        double Dm1 = Do1 - (w0v * Ux10 + w1v * Ux11);
        double Em  = Eo  - (w0v * Uu0 + w1v * Uu1);

        double den1 = -(A00 + A11);
        double den2 = A00 * A11 - A01 * A10;
        double Mm00 = A00 - Bm0 * Dm0, Mm01 = A01 - Bm0 * Dm1;
        double Mm10 = A10 - Bm1 * Dm0, Mm11 = A11 - Bm1 * Dm1;
        double num0 = Em;
        double num1 = -(Mm00 + Mm11) + (Em - 1.0) * den1;
        double num2 = (Mm00 * Mm11 - Mm01 * Mm10) + (Em - 1.0) * den2;

        // ---- poles (eigenvalues of A; real & distinct for this RC ladder) ----
        double trA  = A00 + A11;                  // = -den1
        double disc = den1 * den1 - 4.0 * den2;
        double sq   = sqrt(disc > 0.0 ? disc : 0.0);
        double L1d  = 0.5 * (trA + sq);
        double L2d  = 0.5 * (trA - sq);
        // partial-fraction residues of (num0 + num1 Q + num2 Q^2)/((1-L1 Q)(1-L2 Q))
        double nv1 = (num0 * L1d + num1) * L1d + num2;   // num(L1)
        double nv2 = (num0 * L2d + num1) * L2d + num2;   // num(L2)
        double C0d =  num2 / den2;
        double C1d =  nv1 / (L1d * sq);
        double C2d = -nv2 / (L2d * sq);
        // pole powers for the scan / circular correction
        double a2 = L1d * L1d, a4 = a2 * a2, a8 = a4 * a4, F16a = a8 * a8;
        double a32 = F16a * F16a, a64 = a32 * a32, a128 = a64 * a64,
               a256 = a128 * a128, a512 = a256 * a256, F1ka = a512 * a512;
        double F4ka = (F1ka * F1ka) * (F1ka * F1ka);
        double b2 = L2d * L2d, b4 = b2 * b2, b8 = b4 * b4, F16b = b8 * b8;
        double b32 = F16b * F16b, b64 = b32 * b32, b128 = b64 * b64,
               b256 = b128 * b128, b512 = b256 * b256, F1kb = b512 * b512;
        double F4kb = (F1kb * F1kb) * (F1kb * F1kb);

        cf[0]  = (float)L1d;
        cf[1]  = (float)L2d;
        cf[2]  = (float)C0d;
        cf[3]  = (float)C1d;
        cf[4]  = (float)C2d;
        cf[5]  = (float)F16a;
        cf[6]  = (float)F16b;
        cf[7]  = (float)(16.0 * log2(L1d));
        cf[8]  = (float)(16.0 * log2(L2d));
        cf[9]  = (float)F1ka;
        cf[10] = (float)F1kb;
        cf[11] = (float)(1.0 / (1.0 - F4ka));
        cf[12] = (float)(1.0 / (1.0 - F4kb));
    }
    __syncthreads();

    const float lam1 = cf[0], lam2 = cf[1];
    const float c0 = cf[2], c1 = cf[3], c2 = cf[4];
    const float f16a = cf[5], f16b = cf[6];
    const float l2a = cf[7], l2b = cf[8];
    const float f1ka = cf[9], f1kb = cf[10];
    const float ioma = cf[11], iomb = cf[12];

    // ---- local partials: r_t = sum_j lam^{15-j} s[j] (both poles) ----
    float w1 = 0.0f, w2 = 0.0f;
#pragma unroll
    for (int j = 0; j < 16; ++j) {
        w1 = fmaf(lam1, w1, s[j]);
        w2 = fmaf(lam2, w2, s[j]);
    }

    // ---- intra-wave weighted inclusive scan (combine factor lam^16) ----
    float f1 = f16a, f2 = f16b;
#pragma unroll
    for (int d = 1; d < 64; d <<= 1) {
        float o1 = __shfl_up(w1, d);
        float o2 = __shfl_up(w2, d);
        if (lane >= d) { w1 = fmaf(f1, o1, w1); w2 = fmaf(f2, o2, w2); }
        f1 *= f1; f2 *= f2;
    }
    if (lane == 63) { Tw[0][wv] = w1; Tw[1][wv] = w2; }
    __syncthreads();

    // ---- cross-wave prefix S_w = sum_{v<w} lam1024^{w-1-v} * T_v ----
    float S1 = 0.0f, S2 = 0.0f;
#pragma unroll
    for (int v = 0; v < 3; ++v) {
        if (v < wv) {
            S1 = fmaf(S1, f1ka, Tw[0][v]);
            S2 = fmaf(S2, f1kb, Tw[1][v]);
        }
    }
    const float el1 = exp2f((float)lane * l2a);   // lam1^{16*lane}
    const float el2 = exp2f((float)lane * l2b);
    // merged inclusive value: W_t = W_intra + lam^{16(lane+1)} * S_w
    w1 = fmaf(el1 * f16a, S1, w1);
    w2 = fmaf(el2 * f16b, S2, w2);
    if (t == 255) { Tot[0] = w1; Tot[1] = w2; }
    // incoming prefix for replay: W_{t-1} (lane 0 takes S_w)
    float p1 = __shfl_up(w1, 1); if (lane == 0) p1 = S1;
    float p2 = __shfl_up(w2, 1); if (lane == 0) p2 = S2;
    __syncthreads();

    // ---- emit: reversed positions m = 16t..16t+15 -> out[2047-m] (t < 128) ----
    if (t < 128) {
        const float K1 = Tot[0] * ioma;           // periodic initial state w[-1]
        const float K2 = Tot[1] * iomb;
        float base1 = el1 * (wv ? f1ka : 1.0f) * lam1 * K1;   // lam1^{16t+1} K1
        float base2 = el2 * (wv ? f1kb : 1.0f) * lam2 * K2;
        float w1r = p1, w2r = p2;
        float yv[16];
#pragma unroll
        for (int j = 0; j < 16; ++j) {
            w1r = fmaf(lam1, w1r, s[j]);
            w2r = fmaf(lam2, w2r, s[j]);
            float acc = c1 * (w1r + base1);
            acc = fmaf(c2, (w2r + base2), acc);
            yv[j] = fmaf(c0, s[j], acc);
            base1 *= lam1; base2 *= lam2;
        }
        float* ob = out + (size_t)b * LSEG;
#pragma unroll
        for (int u = 0; u < 4; ++u) {
            v4f o;
            o.x = yv[4 * u + 3]; o.y = yv[4 * u + 2];
            o.z = yv[4 * u + 1]; o.w = yv[4 * u + 0];
            *(v4f*)(ob + (2044 - 16 * t - 4 * u)) = o;
        }
    }
}

extern "C" void kernel_launch(void* const* d_in, const int* in_sizes, int n_in,
                              void* d_out, int out_size, void* d_ws, size_t ws_size,
                              hipStream_t stream) {
    const float* x     = (const float*)d_in[0];
    const float* cond  = (const float*)d_in[1];
    const float* state = (const float*)d_in[2];
    const float* a_rg  = (const float*)d_in[3];
    const float* a_r1  = (const float*)d_in[4];
    const float* a_c1  = (const float*)d_in[5];
    const float* a_c2  = (const float*)d_in[6];
    const float* c_w   = (const float*)d_in[7];
    const float* c_b   = (const float*)d_in[8];
    float* out = (float*)d_out;

    const int B = in_sizes[1];          // cond is [B,1]

    preamp_iir_kernel<<<dim3(B), dim3(256), 0, stream>>>(
        x, state, cond, a_rg, a_r1, a_c1, a_c2, c_w, c_b, out, B);
}

// Round 9
// 104.080 us; speedup vs baseline: 1.1472x; 1.0199x over previous
//
#include <hip/hip_runtime.h>
#include <math.h>

#define NFFT 4096
#define LSEG 2048   // L
#define SSZ 4096    // STATE_SIZE

typedef float v4f __attribute__((ext_vector_type(4)));

// out = irfft(rfft(s) * H)[-L:] with 2nd-order rational H(z), z = e^{-i theta}
// == CIRCULAR biquad, run causally on the REVERSED signal s'[m] = s[4095-m].
// Partial fractions (poles l1,l2 real, distinct, in (0,1)):
//   y' = c0 s' + c1 w1 + c2 w2,   wi = li*wi + s'   (weighted prefix scan)
// Circular wrap folded into the scan seed: w_c[m0-1] = W[m0-1] + li^{m0} * K,
//   K = W_total / (1 - li^4096)  -- the recurrence then propagates li^{m+1}K.
// Output needs only m in [0,2048) of the reversed stream (threads 0..127).
__global__ __launch_bounds__(256, 4)
void preamp_iir_kernel(const float* __restrict__ x,
                       const float* __restrict__ state,
                       const float* __restrict__ cond,
                       const float* __restrict__ a_rg,
                       const float* __restrict__ a_r1,
                       const float* __restrict__ a_c1,
                       const float* __restrict__ a_c2,
                       const float* __restrict__ cond_w,
                       const float* __restrict__ cond_b,
                       float* __restrict__ out, int B) {
    __shared__ float cf[13];     // lam1,lam2,c0,c1,c2,f16a,f16b,l2a,l2b,f1ka,f1kb,ioma,iomb
    __shared__ float Tw[2][4];   // per-wave scan totals, per pole

    const int t = threadIdx.x;
    const int b = blockIdx.x;
    const int lane = t & 63;
    const int wv = t >> 6;

    const float* xb  = x + (size_t)b * LSEG;
    const float* stb = state + (size_t)b * SSZ + (SSZ - LSEG);

    // ---- reversed load: s[j] = buf[4095 - (16t + j)], buf = [state_tail, x] ----
    float s[16];
    if (t < 128) {
#pragma unroll
        for (int u = 0; u < 4; ++u) {
            const int g0 = 4092 - 16 * t - 4 * u;      // >= 2048
            v4f v = *(const v4f*)(xb + (g0 - LSEG));
            s[4 * u + 0] = v.w; s[4 * u + 1] = v.z;
            s[4 * u + 2] = v.y; s[4 * u + 3] = v.x;
        }
    } else {
#pragma unroll
        for (int u = 0; u < 4; ++u) {
            const int g0 = 4092 - 16 * t - 4 * u;      // in [0, 2044]
            v4f v = *(const v4f*)(stb + g0);
            s[4 * u + 0] = v.w; s[4 * u + 1] = v.z;
            s[4 * u + 2] = v.y; s[4 * u + 3] = v.x;
        }
    }

    // ---- coefficient computation (thread 0, fp64 DK-method algebra) ----
    if (t == 0) {
        const double RG = (0.9 + (double)(1.0f / (1.0f + expf(-a_rg[0]))) * 0.2) * 1.0e6;
        const double R1 = (0.99 + (double)(1.0f / (1.0f + expf(-a_r1[0]))) * 0.02) * 4.7e5;
        const double C1 = (0.9 + (double)(1.0f / (1.0f + expf(-a_c1[0]))) * 0.2) * 3.3e-9;
        const double C2 = (0.9 + (double)(1.0f / (1.0f + expf(-a_c2[0]))) * 0.2) * 1.0e-9;
        const double g1 = 1.0 / R1;
        const double gc1 = 2.0 * C1 * 44100.0;
        const double gc2 = 2.0 * C2 * 44100.0;

        float zf = cond[b] * cond_w[0] + cond_b[0];
        float pot = 1.0f / (1.0f + expf(-zf));
        float prf = (powf(10.0f, pot) - 1.0f) / 9.0f;
        prf = fminf(fmaxf(prf, 1e-4f), 1.0f - 1e-4f);
        const double p = (double)prf;

        // Analytic So^{-1}
        const double ds = gc1 + g1;
        double S[4][4] = {
            {0.0, 0.0,        0.0,       1.0},
            {0.0, 1.0 / ds,   0.0,       gc1 / ds},
            {0.0, 0.0,        1.0 / gc2, 0.0},
            {1.0, gc1 / ds,   0.0,       -gc1 * g1 / ds}};

        double Q00 = S[1][1] - S[1][2] - S[2][1] + S[2][2];
        double Q01 = S[1][2] - S[2][2];
        double Q10 = S[2][1] - S[2][2];
        double Q11 = S[2][2];

        double Ux00 = S[0][1] - S[0][2] - S[1][1] + S[1][2];
        double Ux01 = S[0][2] - S[1][2];
        double Ux10 = S[2][1] - S[2][2];
        double Ux11 = S[2][2];

        double Uo0 = S[2][1] - S[2][2], Uo1 = S[2][2];
        double Uu0 = S[3][1] - S[3][2], Uu1 = S[3][2];

        double P00 = S[0][0] - S[0][1] - S[1][0] + S[1][1];
        double P01 = S[0][2] - S[1][2];
        double P10 = S[2][0] - S[2][1];
        double P11 = S[2][2];

        double Ao00 = 2.0 * gc1 * P00 - 1.0, Ao01 = 2.0 * gc1 * P01;
        double Ao10 = 2.0 * gc2 * P10,       Ao11 = 2.0 * gc2 * P11 - 1.0;

        double Bo0 = 2.0 * gc1 * (S[0][3] - S[1][3]);
        double Bo1 = 2.0 * gc2 * S[2][3];

        double Do0 = S[2][0] - S[2][1], Do1 = S[2][2];
        double Eo  = S[2][3];

        double T00 = 2.0 * gc1 * Ux00, T01 = 2.0 * gc1 * Ux01;
        double T10 = 2.0 * gc2 * Ux10, T11 = 2.0 * gc2 * Ux11;

        double d0 = (1.0 - p) * RG, d1v = p * RG;
        double M00 = d0 + Q00, M01 = Q01, M10 = Q10, M11 = d1v + Q11;
        double idet = 1.0 / (M00 * M11 - M01 * M10);
        double G00 =  M11 * idet, G01 = -M01 * idet;
        double G10 = -M10 * idet, G11 =  M00 * idet;

        double TG00 = T00 * G00 + T01 * G10, TG01 = T00 * G01 + T01 * G11;
        double TG10 = T10 * G00 + T11 * G10, TG11 = T10 * G01 + T11 * G11;

        double A00 = Ao00 - (TG00 * Ux00 + TG01 * Ux01);
        double A01 = Ao01 - (TG00 * Ux10 + TG01 * Ux11);
        double A10 = Ao10 - (TG10 * Ux00 + TG11 * Ux01);
        double A11 = Ao11 - (TG10 * Ux10 + TG11 * Ux11);

        double Bm0 = Bo0 - (TG00 * Uu0 + TG01 * Uu1);
        double Bm1 = Bo1 - (TG10 * Uu0 + TG11 * Uu1);

        double w0v = Uo0 * G00 + Uo1 * G10, w1v = Uo0 * G01 + Uo1 * G11;
        double Dm0 = Do0 - (w0v * Ux00 + w1v * Ux01);
        double Dm1 = Do1 - (w0v * Ux10 + w1v * Ux11);
        double Em  = Eo  - (w0v * Uu0 + w1v * Uu1);

        double den1 = -(A00 + A11);
        double den2 = A00 * A11 - A01 * A10;
        double Mm00 = A00 - Bm0 * Dm0, Mm01 = A01 - Bm0 * Dm1;
        double Mm10 = A10 - Bm1 * Dm0, Mm11 = A11 - Bm1 * Dm1;
        double num0 = Em;
        double num1 = -(Mm00 + Mm11) + (Em - 1.0) * den1;
        double num2 = (Mm00 * Mm11 - Mm01 * Mm10) + (Em - 1.0) * den2;

        // ---- poles (eigenvalues of A; real & distinct for this RC ladder) ----
        double trA  = A00 + A11;                  // = -den1
        double disc = den1 * den1 - 4.0 * den2;
        double sq   = sqrt(disc > 0.0 ? disc : 0.0);
        double L1d  = 0.5 * (trA + sq);
        double L2d  = 0.5 * (trA - sq);
        // partial-fraction residues
        double nv1 = (num0 * L1d + num1) * L1d + num2;   // num(L1)
        double nv2 = (num0 * L2d + num1) * L2d + num2;   // num(L2)
        double C0d =  num2 / den2;
        double C1d =  nv1 / (L1d * sq);
        double C2d = -nv2 / (L2d * sq);
        // pole powers for the scan / circular correction
        double a2 = L1d * L1d, a4 = a2 * a2, a8 = a4 * a4, F16a = a8 * a8;
        double a32 = F16a * F16a, a64 = a32 * a32, a128 = a64 * a64,
               a256 = a128 * a128, a512 = a256 * a256, F1ka = a512 * a512;
        double F4ka = (F1ka * F1ka) * (F1ka * F1ka);
        double b2 = L2d * L2d, b4 = b2 * b2, b8 = b4 * b4, F16b = b8 * b8;
        double b32 = F16b * F16b, b64 = b32 * b32, b128 = b64 * b64,
               b256 = b128 * b128, b512 = b256 * b256, F1kb = b512 * b512;
        double F4kb = (F1kb * F1kb) * (F1kb * F1kb);

        cf[0]  = (float)L1d;
        cf[1]  = (float)L2d;
        cf[2]  = (float)C0d;
        cf[3]  = (float)C1d;
        cf[4]  = (float)C2d;
        cf[5]  = (float)F16a;
        cf[6]  = (float)F16b;
        cf[7]  = 16.0f * log2f((float)L1d);      // float HW log2 (was fp64 sw)
        cf[8]  = 16.0f * log2f((float)L2d);
        cf[9]  = (float)F1ka;
        cf[10] = (float)F1kb;
        cf[11] = (float)(1.0 / (1.0 - F4ka));
        cf[12] = (float)(1.0 / (1.0 - F4kb));
    }
    __syncthreads();

    const float lam1 = cf[0], lam2 = cf[1];
    const float c0 = cf[2], c1 = cf[3], c2 = cf[4];
    const float f16a = cf[5], f16b = cf[6];
    const float l2a = cf[7], l2b = cf[8];
    const float f1ka = cf[9], f1kb = cf[10];
    const float ioma = cf[11], iomb = cf[12];

    // ---- local partials: r_t = sum_j lam^{15-j} s[j] (both poles) ----
    float w1 = 0.0f, w2 = 0.0f;
#pragma unroll
    for (int j = 0; j < 16; ++j) {
        w1 = fmaf(lam1, w1, s[j]);
        w2 = fmaf(lam2, w2, s[j]);
    }

    // ---- intra-wave weighted inclusive scan (combine factor lam^16) ----
    float f1 = f16a, f2 = f16b;
#pragma unroll
    for (int d = 1; d < 64; d <<= 1) {
        float o1 = __shfl_up(w1, d);
        float o2 = __shfl_up(w2, d);
        if (lane >= d) { w1 = fmaf(f1, o1, w1); w2 = fmaf(f2, o2, w2); }
        f1 *= f1; f2 *= f2;
    }
    if (lane == 63) { Tw[0][wv] = w1; Tw[1][wv] = w2; }
    __syncthreads();

    // ---- emit: only waves 0,1 (reversed positions m = 16t..16t+15 -> out[2047-m]) ----
    if (t < 128) {
        // cross-wave prefix (wave 0: none; wave 1: wave 0's total)
        float S1 = 0.0f, S2 = 0.0f;
        if (wv == 1) { S1 = Tw[0][0]; S2 = Tw[1][0]; }
        const float el1 = exp2f((float)lane * l2a);   // lam1^{16*lane}
        const float el2 = exp2f((float)lane * l2b);
        // merged inclusive value, then incoming prefix W[m0-1]
        w1 = fmaf(el1 * f16a, S1, w1);
        w2 = fmaf(el2 * f16b, S2, w2);
        float p1 = __shfl_up(w1, 1); if (lane == 0) p1 = S1;
        float p2 = __shfl_up(w2, 1); if (lane == 0) p2 = S2;

        // block totals (= W[4095]) from the 4 wave totals; periodic K
        float K1 = fmaf(fmaf(fmaf(Tw[0][0], f1ka, Tw[0][1]), f1ka, Tw[0][2]), f1ka, Tw[0][3]) * ioma;
        float K2 = fmaf(fmaf(fmaf(Tw[1][0], f1kb, Tw[1][1]), f1kb, Tw[1][2]), f1kb, Tw[1][3]) * iomb;

        // seed the replay with the periodic correction: w_c[m0-1] = p + lam^{16t} * K
        const float pw1 = el1 * (wv ? f1ka : 1.0f);   // lam1^{16t}
        const float pw2 = el2 * (wv ? f1kb : 1.0f);
        float w1r = fmaf(pw1, K1, p1);
        float w2r = fmaf(pw2, K2, p2);

        float* ob = out + (size_t)b * LSEG;
#pragma unroll
        for (int u = 0; u < 4; ++u) {
            float y0, y1, y2, y3;
            {
                const float sv = s[4 * u + 0];
                w1r = fmaf(lam1, w1r, sv); w2r = fmaf(lam2, w2r, sv);
                y0 = fmaf(c0, sv, fmaf(c2, w2r, c1 * w1r));
            }
            {
                const float sv = s[4 * u + 1];
                w1r = fmaf(lam1, w1r, sv); w2r = fmaf(lam2, w2r, sv);
                y1 = fmaf(c0, sv, fmaf(c2, w2r, c1 * w1r));
            }
            {
                const float sv = s[4 * u + 2];
                w1r = fmaf(lam1, w1r, sv); w2r = fmaf(lam2, w2r, sv);
                y2 = fmaf(c0, sv, fmaf(c2, w2r, c1 * w1r));
            }
            {
                const float sv = s[4 * u + 3];
                w1r = fmaf(lam1, w1r, sv); w2r = fmaf(lam2, w2r, sv);
                y3 = fmaf(c0, sv, fmaf(c2, w2r, c1 * w1r));
            }
            v4f o;
            o.x = y3; o.y = y2; o.z = y1; o.w = y0;   // out idx 2044-16t-4u .. +3
            *(v4f*)(ob + (2044 - 16 * t - 4 * u)) = o;
        }
    }
}

extern "C" void kernel_launch(void* const* d_in, const int* in_sizes, int n_in,
                              void* d_out, int out_size, void* d_ws, size_t ws_size,
                              hipStream_t stream) {
    const float* x     = (const float*)d_in[0];
    const float* cond  = (const float*)d_in[1];
    const float* state = (const float*)d_in[2];
    const float* a_rg  = (const float*)d_in[3];
    const float* a_r1  = (const float*)d_in[4];
    const float* a_c1  = (const float*)d_in[5];
    const float* a_c2  = (const float*)d_in[6];
    const float* c_w   = (const float*)d_in[7];
    const float* c_b   = (const float*)d_in[8];
    float* out = (float*)d_out;

    const int B = in_sizes[1];          // cond is [B,1]

    preamp_iir_kernel<<<dim3(B), dim3(256), 0, stream>>>(
        x, state, cond, a_rg, a_r1, a_c1, a_c2, c_w, c_b, out, B);
}